// Round 1
// 5658.959 us; speedup vs baseline: 1.3417x; 1.3417x over previous
//
#include <hip/hip_runtime.h>
#include <hip/hip_bf16.h>
#include <math.h>

#define HH    1024
#define TT    64
#define NBAT  256
#define G3    3072
#define IN0   150
#define IN0P  160   // padded K for layer 0
#define NCLS  60
#define ENC_W 2048

typedef float  f32x4 __attribute__((ext_vector_type(4)));
typedef short  s16x8 __attribute__((ext_vector_type(8)));

#define GLOAD16(gsrc, ldst) \
  __builtin_amdgcn_global_load_lds((const __attribute__((address_space(1))) unsigned int*)(gsrc), \
                                   (__attribute__((address_space(3))) unsigned int*)(ldst), 16, 0, 0)

static __device__ inline short f2bf(float f) {
    __hip_bfloat16 h = __float2bfloat16(f);
    return *(short*)&h;
}

// ---------------- BatchNorm stats ----------------
__global__ void bigru_bn_stats(const float* __restrict__ x,
                               float* __restrict__ mean, float* __restrict__ istd) {
    int f = blockIdx.x;
    int tid = threadIdx.x;
    double s = 0.0, s2 = 0.0;
    for (int i = tid; i < NBAT * TT; i += blockDim.x) {
        float v = x[(size_t)i * IN0 + f];
        s += v; s2 += (double)v * v;
    }
    __shared__ double sh[256], sh2[256];
    sh[tid] = s; sh2[tid] = s2;
    __syncthreads();
    for (int off = 128; off > 0; off >>= 1) {
        if (tid < off) { sh[tid] += sh[tid + off]; sh2[tid] += sh2[tid + off]; }
        __syncthreads();
    }
    if (tid == 0) {
        double m = sh[0] / (NBAT * TT);
        double var = sh2[0] / (NBAT * TT) - m * m;
        mean[f] = (float)m;
        istd[f] = (float)(1.0 / sqrt(var + 1e-5));
    }
}

// ---------------- BN apply -> padded bf16 [16384][160] ----------------
__global__ void bigru_bn_apply_bf16(const float* __restrict__ x,
                                    const float* __restrict__ mean, const float* __restrict__ istd,
                                    const float* __restrict__ gamma, const float* __restrict__ beta,
                                    short* __restrict__ xn) {
    int idx = blockIdx.x * blockDim.x + threadIdx.x;
    if (idx >= NBAT * TT * IN0P) return;
    int f = idx % IN0P;
    int r = idx / IN0P;
    float v = 0.f;
    if (f < IN0) v = (x[(size_t)r * IN0 + f] - mean[f]) * istd[f] * gamma[f] + beta[f];
    xn[idx] = f2bf(v);
}

// ---------------- Convert w_ih_0 [2][3072][150] -> padded bf16 [2][3072][160] ----
__global__ void bigru_cvt_wih0(const float* __restrict__ src, short* __restrict__ dst) {
    int idx = blockIdx.x * blockDim.x + threadIdx.x;
    if (idx >= 2 * G3 * IN0P) return;
    int f = idx % IN0P;
    int r = idx / IN0P;
    float v = (f < IN0) ? src[(size_t)r * IN0 + f] : 0.f;
    dst[idx] = f2bf(v);
}

// ---------------- Generic f32 -> bf16 convert (n % 4 == 0) ----------------
__global__ void bigru_cvt4(const float* __restrict__ src, short* __restrict__ dst, int n4) {
    int i = blockIdx.x * blockDim.x + threadIdx.x;
    if (i >= n4) return;
    float4 v = ((const float4*)src)[i];
    short4 o;
    o.x = f2bf(v.x); o.y = f2bf(v.y); o.z = f2bf(v.z); o.w = f2bf(v.w);
    ((short4*)dst)[i] = o;
}

// ---------------- Bulk gi GEMM: C[2][Mchunk][3072] = A @ W^T + b_ih ----------------
// A rows map r -> (tt = r>>8, n = r&255) -> Abase + (n*64 + t0 + tt)*ldA
// 128x128 tile, BK=32, 4 waves of 64x64, mfma 16x16x32 bf16
__global__ __launch_bounds__(256)
void bigru_gi_gemm(const short* __restrict__ Abase, int ldA, int K,
                   const short* __restrict__ W,       // [2][3072][K]
                   const float* __restrict__ b_ih,    // [2][3072]
                   float* __restrict__ gi,            // [2][Mchunk][3072]
                   int t0, int Mchunk) {
    int d    = blockIdx.z;
    int col0 = blockIdx.x * 128;
    int row0 = blockIdx.y * 128;

    __shared__ short As[128][32];
    __shared__ short Bs[128][32];

    int tid  = threadIdx.x;
    int lane = tid & 63;
    int w    = tid >> 6;
    int wm   = w & 1, wn = w >> 1;

    f32x4 acc[4][4];
    #pragma unroll
    for (int i = 0; i < 4; ++i)
        #pragma unroll
        for (int j = 0; j < 4; ++j)
            acc[i][j] = (f32x4){0.f, 0.f, 0.f, 0.f};

    const short* Wd = W + (size_t)d * G3 * K;
    int sr = lane >> 2;
    int sc = (lane & 3) * 8;

    for (int k0 = 0; k0 < K; k0 += 32) {
        #pragma unroll
        for (int q = 0; q < 2; ++q) {
            int r  = w * 32 + q * 16 + sr;            // 0..127
            int gr = row0 + r;
            int tt = gr >> 8, n = gr & 255;
            const short* ga = Abase + (size_t)(n * TT + t0 + tt) * ldA + k0 + sc;
            GLOAD16(ga, &As[w * 32 + q * 16][0]);
            const short* gb = Wd + (size_t)(col0 + r) * K + k0 + sc;
            GLOAD16(gb, &Bs[w * 32 + q * 16][0]);
        }
        __syncthreads();

        int fr = lane & 15, fq = (lane >> 4) * 8;
        s16x8 a[4], b[4];
        #pragma unroll
        for (int i = 0; i < 4; ++i) a[i] = *(const s16x8*)&As[wm * 64 + i * 16 + fr][fq];
        #pragma unroll
        for (int j = 0; j < 4; ++j) b[j] = *(const s16x8*)&Bs[wn * 64 + j * 16 + fr][fq];
        #pragma unroll
        for (int i = 0; i < 4; ++i)
            #pragma unroll
            for (int j = 0; j < 4; ++j)
                acc[i][j] = __builtin_amdgcn_mfma_f32_16x16x32_bf16(a[i], b[j], acc[i][j], 0, 0, 0);
        __syncthreads();
    }

    int fr = lane & 15, quad = lane >> 4;
    #pragma unroll
    for (int j = 0; j < 4; ++j) {
        int c = col0 + wn * 64 + j * 16 + fr;
        float bias = b_ih[d * G3 + c];
        #pragma unroll
        for (int i = 0; i < 4; ++i) {
            #pragma unroll
            for (int reg = 0; reg < 4; ++reg) {
                int r = row0 + wm * 64 + i * 16 + quad * 4 + reg;
                gi[((size_t)d * Mchunk + r) * G3 + c] = acc[i][j][reg] + bias;
            }
        }
    }
}

// ---------------- Fused persistent recurrence over Tc steps ----------------
// Cooperative launch, grid = 256 blocks x 256 threads, 1 block/CU (96 KiB LDS).
// Block b: d = b&1, mt = (b>>1)&1 (128-row half), ct = b>>2 (16 h-cols).
// W slice [48 wrows][1024] staged ONCE into LDS (XOR-swizzled via pre-swizzled
// global source, read with matching swizzle -> bank-balanced ds_read_b128).
// h kept in registers across steps; A (hbf) read direct from global (L2-res).
// Between steps: device-scope barrier over the 64 blocks sharing (d, mt).
__global__ __launch_bounds__(256, 1)
void bigru_steps_fused(const short* __restrict__ w_hh,   // [2][3072][1024] bf16
                       const float* __restrict__ b_hh,   // [2][3072]
                       const float* __restrict__ gi,     // [2][Mchunk][3072]
                       float* __restrict__ h,            // [2][256][1024] fp32 master
                       short* __restrict__ hbf,          // [2buf][2][256][1024] bf16
                       float* __restrict__ enc,          // null unless last layer
                       short* __restrict__ enc_bf,       // null on last layer
                       unsigned int* __restrict__ bar,   // [4 groups * 32]
                       int t0, int Tc, int Mchunk) {
    __shared__ short Bs[48 * 1024];   // 96 KiB

    int b   = blockIdx.x;
    int d   = b & 1;
    int mt  = (b >> 1) & 1;
    int ct  = b >> 2;              // 0..63
    int grp = b & 3;

    int tid  = threadIdx.x;
    int lane = tid & 63;
    int w    = tid >> 6;
    int fr   = lane & 15;
    int quad = lane >> 4;
    int sw   = fr & 7;

    int j0 = ct * 16;
    int m0 = mt * 128;
    int row_base = m0 + w * 32;
    int jcol = j0 + fr;

    const short* Wd = w_hh + (size_t)d * G3 * HH;

    // ---- stage W slice into LDS once (swizzled source, linear dest) ----
    // chunk c covers 8 rows? no: covers half a row (1024B). c = rr*2 + kh.
    #pragma unroll
    for (int q = 0; q < 24; ++q) {
        int c  = w * 24 + q;
        int rr = c >> 1, kh = c & 1;
        int g  = rr >> 4, jc = rr & 15;
        const short* src = Wd + (size_t)(g * HH + j0 + jc) * HH
                         + (size_t)(kh * 64 + (lane ^ (rr & 7))) * 8;
        GLOAD16(src, &Bs[rr * 1024 + kh * 512]);
    }

    // ---- per-lane persistent h registers (fp32) ----
    float hreg[2][4];
    #pragma unroll
    for (int i = 0; i < 2; ++i)
        #pragma unroll
        for (int r = 0; r < 4; ++r) {
            int n = row_base + i * 16 + quad * 4 + r;
            hreg[i][r] = h[((size_t)d * NBAT + n) * HH + jcol];
        }

    float bhr = b_hh[d * G3 + jcol];
    float bhz = b_hh[d * G3 + HH + jcol];
    float bhn = b_hh[d * G3 + 2 * HH + jcol];

    __syncthreads();   // Bs staged (syncthreads drains vmcnt)

    for (int tt = 0; tt < Tc; ++tt) {
        int t = t0 + tt;
        const short* hb = hbf + ((size_t)((t & 1) * 2 + d)) * NBAT * HH;
        short*       ho = hbf + ((size_t)(((t + 1) & 1) * 2 + d)) * NBAT * HH;

        // prefetch gi for this step (independent of K loop, hides LLC latency)
        float gir[8], giz[8], gin[8];
        {
            size_t gbase = ((size_t)d * Mchunk + (size_t)tt * NBAT) * G3 + jcol;
            #pragma unroll
            for (int i = 0; i < 2; ++i)
                #pragma unroll
                for (int r = 0; r < 4; ++r) {
                    int n = row_base + i * 16 + quad * 4 + r;
                    size_t gg = gbase + (size_t)n * G3;
                    gir[i * 4 + r] = gi[gg];
                    giz[i * 4 + r] = gi[gg + HH];
                    gin[i * 4 + r] = gi[gg + 2 * HH];
                }
        }

        f32x4 acc[2][3];
        #pragma unroll
        for (int i = 0; i < 2; ++i)
            #pragma unroll
            for (int g = 0; g < 3; ++g)
                acc[i][g] = (f32x4){0.f, 0.f, 0.f, 0.f};

        const short* hrow0 = hb + (size_t)(row_base + fr) * HH + quad * 8;
        const short* hrow1 = hrow0 + (size_t)16 * HH;

        // K loop: no barriers, A direct from global, B from persistent LDS
        #pragma unroll 8
        for (int k0 = 0; k0 < HH; k0 += 32) {
            s16x8 a0 = *(const s16x8*)(hrow0 + k0);
            s16x8 a1 = *(const s16x8*)(hrow1 + k0);
            int ks = (k0 >> 3) + quad;
            #pragma unroll
            for (int g = 0; g < 3; ++g) {
                s16x8 bg = *(const s16x8*)&Bs[(g * 16 + fr) * 1024 + ((ks ^ sw) << 3)];
                acc[0][g] = __builtin_amdgcn_mfma_f32_16x16x32_bf16(a0, bg, acc[0][g], 0, 0, 0);
                acc[1][g] = __builtin_amdgcn_mfma_f32_16x16x32_bf16(a1, bg, acc[1][g], 0, 0, 0);
            }
        }

        // gates + state update (all in registers)
        #pragma unroll
        for (int i = 0; i < 2; ++i) {
            #pragma unroll
            for (int r = 0; r < 4; ++r) {
                int idx8 = i * 4 + r;
                int n = row_base + i * 16 + quad * 4 + r;
                float hrv = acc[i][0][r] + bhr;
                float hzv = acc[i][1][r] + bhz;
                float hnv = acc[i][2][r] + bhn;
                float rg = 1.f / (1.f + __expf(-(gir[idx8] + hrv)));
                float zg = 1.f / (1.f + __expf(-(giz[idx8] + hzv)));
                float ng = tanhf(gin[idx8] + rg * hnv);
                float hnew = (1.f - zg) * ng + zg * hreg[i][r];
                hreg[i][r] = hnew;
                ho[(size_t)n * HH + jcol] = f2bf(hnew);
                size_t eidx = ((size_t)n * TT + t) * ENC_W + (size_t)d * HH + jcol;
                if (enc_bf) enc_bf[eidx] = f2bf(hnew);
                if (enc)    enc[eidx]    = hnew;
            }
        }

        if (tt == Tc - 1) {   // persist fp32 h for the next chunk
            #pragma unroll
            for (int i = 0; i < 2; ++i)
                #pragma unroll
                for (int r = 0; r < 4; ++r) {
                    int n = row_base + i * 16 + quad * 4 + r;
                    h[((size_t)d * NBAT + n) * HH + jcol] = hreg[i][r];
                }
        } else {
            // ---- inter-step barrier over the 64 blocks of group (d, mt) ----
            __syncthreads();                       // all waves' stores drained
            if (tid == 0) {
                unsigned int* c = &bar[grp * 32];
                __hip_atomic_fetch_add(c, 1u, __ATOMIC_RELEASE, __HIP_MEMORY_SCOPE_AGENT);
                unsigned tgt = 64u * (unsigned)(tt + 1);
                while (__hip_atomic_load(c, __ATOMIC_ACQUIRE, __HIP_MEMORY_SCOPE_AGENT) < tgt)
                    __builtin_amdgcn_s_sleep(2);
            }
            __syncthreads();
        }
    }
}

// ---------------- FC head ----------------
__global__ void bigru_fc(const float* __restrict__ enc, const float* __restrict__ fc_w,
                         const float* __restrict__ fc_b, float* __restrict__ out) {
    int n = blockIdx.x;
    int tid = threadIdx.x;
    __shared__ float hbuf[ENC_W];
    for (int k = tid; k < ENC_W; k += blockDim.x)
        hbuf[k] = enc[(size_t)n * TT * ENC_W + (size_t)(TT - 1) * ENC_W + k];
    __syncthreads();
    if (tid < NCLS) {
        float acc = fc_b[tid];
        for (int k = 0; k < ENC_W; ++k)
            acc += hbuf[k] * fc_w[(size_t)tid * ENC_W + k];
        out[(size_t)n * NCLS + tid] = acc;
    }
}

extern "C" void kernel_launch(void* const* d_in, const int* in_sizes, int n_in,
                              void* d_out, int out_size, void* d_ws, size_t ws_size,
                              hipStream_t stream) {
    const float* x        = (const float*)d_in[0];
    const float* bn_gamma = (const float*)d_in[1];
    const float* bn_beta  = (const float*)d_in[2];
    const float* w_ih[3]  = {(const float*)d_in[3], (const float*)d_in[7],  (const float*)d_in[11]};
    const float* w_hh[3]  = {(const float*)d_in[4], (const float*)d_in[8],  (const float*)d_in[12]};
    const float* b_ih[3]  = {(const float*)d_in[5], (const float*)d_in[9],  (const float*)d_in[13]};
    const float* b_hh[3]  = {(const float*)d_in[6], (const float*)d_in[10], (const float*)d_in[14]};
    const float* fc_w     = (const float*)d_in[15];
    const float* fc_b     = (const float*)d_in[16];

    float* out = (float*)d_out;
    float* enc = out + NBAT * NCLS;                       // [256][64][2048] fp32

    // ---- workspace bump allocator (256B aligned) ----
    char* base = (char*)d_ws;
    size_t off = 0;
    auto alloc = [&](size_t bytes) {
        void* p = base + off;
        off += (bytes + 255) & ~(size_t)255;
        return p;
    };
    float* mean      = (float*)alloc(IN0 * 4);
    float* istd      = (float*)alloc(IN0 * 4);
    short* xn_bf     = (short*)alloc((size_t)NBAT * TT * IN0P * 2);
    short* wih0_bf   = (short*)alloc((size_t)2 * G3 * IN0P * 2);
    short* wih_bf    = (short*)alloc((size_t)2 * G3 * ENC_W * 2);
    short* whh_bf    = (short*)alloc((size_t)2 * G3 * HH * 2);
    float* h         = (float*)alloc((size_t)2 * NBAT * HH * 4);
    short* hbf       = (short*)alloc((size_t)2 * 2 * NBAT * HH * 2);  // double buffer
    short* enc_bf    = (short*)alloc((size_t)NBAT * TT * ENC_W * 2);
    unsigned int* bar = (unsigned int*)alloc(4 * 32 * sizeof(unsigned int));
    size_t fixed = off;

    // pick largest Tc whose gi chunk fits in remaining ws
    int Tc = 1;
    for (int cand : {16, 8, 4, 2, 1}) {
        size_t gi_bytes = (size_t)2 * NBAT * cand * G3 * 4;
        if (fixed + gi_bytes + 1024 <= ws_size) { Tc = cand; break; }
    }
    float* gi = (float*)alloc((size_t)2 * NBAT * Tc * G3 * 4);
    int Mchunk = NBAT * Tc;

    // ---- BN ----
    bigru_bn_stats<<<IN0, 256, 0, stream>>>(x, mean, istd);
    bigru_bn_apply_bf16<<<(NBAT * TT * IN0P + 255) / 256, 256, 0, stream>>>(
        x, mean, istd, bn_gamma, bn_beta, xn_bf);

    // ---- weight conversions (layer-0 padded) ----
    bigru_cvt_wih0<<<(2 * G3 * IN0P + 255) / 256, 256, 0, stream>>>(w_ih[0], wih0_bf);

    for (int l = 0; l < 3; ++l) {
        if (l > 0) {
            int n4 = (2 * G3 * ENC_W) / 4;
            bigru_cvt4<<<(n4 + 255) / 256, 256, 0, stream>>>(w_ih[l], wih_bf, n4);
        }
        {
            int n4 = (2 * G3 * HH) / 4;
            bigru_cvt4<<<(n4 + 255) / 256, 256, 0, stream>>>(w_hh[l], whh_bf, n4);
        }
        hipMemsetAsync(h, 0, (size_t)2 * NBAT * HH * 4, stream);
        hipMemsetAsync(hbf, 0, (size_t)2 * 2 * NBAT * HH * 2, stream);

        const short* Abase = (l == 0) ? xn_bf : enc_bf;
        int ldA = (l == 0) ? IN0P : ENC_W;
        int K   = (l == 0) ? IN0P : ENC_W;
        const short* W = (l == 0) ? wih0_bf : wih_bf;

        for (int t0 = 0; t0 < TT; t0 += Tc) {
            bigru_gi_gemm<<<dim3(G3 / 128, Mchunk / 128, 2), 256, 0, stream>>>(
                Abase, ldA, K, W, b_ih[l], gi, t0, Mchunk);

            hipMemsetAsync(bar, 0, 4 * 32 * sizeof(unsigned int), stream);

            const short* whh_c   = whh_bf;
            const float* bhh_c   = b_hh[l];
            const float* gi_c    = gi;
            float*       h_c     = h;
            short*       hbf_c   = hbf;
            float*       enc_c   = (l == 2) ? enc : nullptr;
            short*       encbf_c = (l == 2) ? nullptr : enc_bf;
            unsigned int* bar_c  = bar;
            int a_t0 = t0, a_tc = Tc, a_mc = Mchunk;
            void* kargs[] = { &whh_c, &bhh_c, &gi_c, &h_c, &hbf_c,
                              &enc_c, &encbf_c, &bar_c, &a_t0, &a_tc, &a_mc };
            hipLaunchCooperativeKernel((const void*)bigru_steps_fused,
                                       dim3(256), dim3(256), kargs, 0, stream);
        }
    }

    bigru_fc<<<NBAT, 256, 0, stream>>>(enc, fc_w, fc_b, out);
}

// Round 4
// 4835.312 us; speedup vs baseline: 1.5703x; 1.1703x over previous
//
#include <hip/hip_runtime.h>
#include <hip/hip_bf16.h>
#include <math.h>

#define HH    1024
#define TT    64
#define NBAT  256
#define G3    3072
#define IN0   150
#define IN0P  160   // padded K for layer 0
#define NCLS  60
#define ENC_W 2048

typedef float  f32x4 __attribute__((ext_vector_type(4)));
typedef short  s16x8 __attribute__((ext_vector_type(8)));

#define GLOAD16(gsrc, ldst) \
  __builtin_amdgcn_global_load_lds((const __attribute__((address_space(1))) unsigned int*)(gsrc), \
                                   (__attribute__((address_space(3))) unsigned int*)(ldst), 16, 0, 0)

static __device__ inline short f2bf(float f) {
    __hip_bfloat16 h = __float2bfloat16(f);
    return *(short*)&h;
}

// ---------------- BatchNorm stats ----------------
__global__ void bigru_bn_stats(const float* __restrict__ x,
                               float* __restrict__ mean, float* __restrict__ istd) {
    int f = blockIdx.x;
    int tid = threadIdx.x;
    double s = 0.0, s2 = 0.0;
    for (int i = tid; i < NBAT * TT; i += blockDim.x) {
        float v = x[(size_t)i * IN0 + f];
        s += v; s2 += (double)v * v;
    }
    __shared__ double sh[256], sh2[256];
    sh[tid] = s; sh2[tid] = s2;
    __syncthreads();
    for (int off = 128; off > 0; off >>= 1) {
        if (tid < off) { sh[tid] += sh[tid + off]; sh2[tid] += sh2[tid + off]; }
        __syncthreads();
    }
    if (tid == 0) {
        double m = sh[0] / (NBAT * TT);
        double var = sh2[0] / (NBAT * TT) - m * m;
        mean[f] = (float)m;
        istd[f] = (float)(1.0 / sqrt(var + 1e-5));
    }
}

// ---------------- BN apply -> padded bf16 [16384][160] ----------------
__global__ void bigru_bn_apply_bf16(const float* __restrict__ x,
                                    const float* __restrict__ mean, const float* __restrict__ istd,
                                    const float* __restrict__ gamma, const float* __restrict__ beta,
                                    short* __restrict__ xn) {
    int idx = blockIdx.x * blockDim.x + threadIdx.x;
    if (idx >= NBAT * TT * IN0P) return;
    int f = idx % IN0P;
    int r = idx / IN0P;
    float v = 0.f;
    if (f < IN0) v = (x[(size_t)r * IN0 + f] - mean[f]) * istd[f] * gamma[f] + beta[f];
    xn[idx] = f2bf(v);
}

// ---------------- Convert w_ih_0 [2][3072][150] -> padded bf16 [2][3072][160] ----
__global__ void bigru_cvt_wih0(const float* __restrict__ src, short* __restrict__ dst) {
    int idx = blockIdx.x * blockDim.x + threadIdx.x;
    if (idx >= 2 * G3 * IN0P) return;
    int f = idx % IN0P;
    int r = idx / IN0P;
    float v = (f < IN0) ? src[(size_t)r * IN0 + f] : 0.f;
    dst[idx] = f2bf(v);
}

// ---------------- Generic f32 -> bf16 convert (n % 4 == 0) ----------------
__global__ void bigru_cvt4(const float* __restrict__ src, short* __restrict__ dst, int n4) {
    int i = blockIdx.x * blockDim.x + threadIdx.x;
    if (i >= n4) return;
    float4 v = ((const float4*)src)[i];
    short4 o;
    o.x = f2bf(v.x); o.y = f2bf(v.y); o.z = f2bf(v.z); o.w = f2bf(v.w);
    ((short4*)dst)[i] = o;
}

// ---------------- Bulk gi GEMM: C[2][Mchunk][3072] = A @ W^T + b_ih ----------------
__global__ __launch_bounds__(256)
void bigru_gi_gemm(const short* __restrict__ Abase, int ldA, int K,
                   const short* __restrict__ W,       // [2][3072][K]
                   const float* __restrict__ b_ih,    // [2][3072]
                   float* __restrict__ gi,            // [2][Mchunk][3072]
                   int t0, int Mchunk) {
    int d    = blockIdx.z;
    int col0 = blockIdx.x * 128;
    int row0 = blockIdx.y * 128;

    __shared__ short As[128][32];
    __shared__ short Bs[128][32];

    int tid  = threadIdx.x;
    int lane = tid & 63;
    int w    = tid >> 6;
    int wm   = w & 1, wn = w >> 1;

    f32x4 acc[4][4];
    #pragma unroll
    for (int i = 0; i < 4; ++i)
        #pragma unroll
        for (int j = 0; j < 4; ++j)
            acc[i][j] = (f32x4){0.f, 0.f, 0.f, 0.f};

    const short* Wd = W + (size_t)d * G3 * K;
    int sr = lane >> 2;
    int sc = (lane & 3) * 8;

    for (int k0 = 0; k0 < K; k0 += 32) {
        #pragma unroll
        for (int q = 0; q < 2; ++q) {
            int r  = w * 32 + q * 16 + sr;            // 0..127
            int gr = row0 + r;
            int tt = gr >> 8, n = gr & 255;
            const short* ga = Abase + (size_t)(n * TT + t0 + tt) * ldA + k0 + sc;
            GLOAD16(ga, &As[w * 32 + q * 16][0]);
            const short* gb = Wd + (size_t)(col0 + r) * K + k0 + sc;
            GLOAD16(gb, &Bs[w * 32 + q * 16][0]);
        }
        __syncthreads();

        int fr = lane & 15, fq = (lane >> 4) * 8;
        s16x8 a[4], b[4];
        #pragma unroll
        for (int i = 0; i < 4; ++i) a[i] = *(const s16x8*)&As[wm * 64 + i * 16 + fr][fq];
        #pragma unroll
        for (int j = 0; j < 4; ++j) b[j] = *(const s16x8*)&Bs[wn * 64 + j * 16 + fr][fq];
        #pragma unroll
        for (int i = 0; i < 4; ++i)
            #pragma unroll
            for (int j = 0; j < 4; ++j)
                acc[i][j] = __builtin_amdgcn_mfma_f32_16x16x32_bf16(a[i], b[j], acc[i][j], 0, 0, 0);
        __syncthreads();
    }

    int fr = lane & 15, quad = lane >> 4;
    #pragma unroll
    for (int j = 0; j < 4; ++j) {
        int c = col0 + wn * 64 + j * 16 + fr;
        float bias = b_ih[d * G3 + c];
        #pragma unroll
        for (int i = 0; i < 4; ++i) {
            #pragma unroll
            for (int reg = 0; reg < 4; ++reg) {
                int r = row0 + wm * 64 + i * 16 + quad * 4 + reg;
                gi[((size_t)d * Mchunk + r) * G3 + c] = acc[i][j][reg] + bias;
            }
        }
    }
}

// ---------------- Fused persistent recurrence over Tc steps (v4) ----------------
// 256 blocks x 512 threads (8 waves, 2/SIMD). Block b: d=b&1, mt=(b>>1)&1,
// ct=b>>2 (16 h-cols). Wave w owns 16 rows (row_base = mt*128 + w*16).
// LDS = 96 KiB persistent W slice + 32 KiB A ring = 128 KiB.
// A staged per-wave via async global_load_lds into a 4-slot x 1KB ring,
// issue-ahead 3; waits: vmcnt(2) steady, DRAIN vmcnt(1)/vmcnt(0) at c=30/31
// (epilogue drain per T3/T4 — missing drain was the round-3 correctness bug).
// gi loads for step t+1 issued BEFORE the inter-step barrier (latency overlaps spin).
__global__ __launch_bounds__(512, 1)
void bigru_steps_fused(const short* __restrict__ w_hh,   // [2][3072][1024] bf16
                       const float* __restrict__ b_hh,   // [2][3072]
                       const float* __restrict__ gi,     // [2][Mchunk][3072]
                       float* __restrict__ h,            // [2][256][1024] fp32 master
                       short* __restrict__ hbf,          // [2buf][2][256][1024] bf16
                       float* __restrict__ enc,          // non-null only on last layer
                       short* __restrict__ enc_bf,       // null on last layer
                       unsigned int* __restrict__ bar,   // [4 groups * 32]
                       int t0, int Tc, int Mchunk) {
    __shared__ short Ws[48 * 1024];     // 96 KiB persistent W slice
    __shared__ short As[8][4][512];     // 32 KiB A ring: 8 waves x 4 slots x 1KB

    int b   = blockIdx.x;
    int d   = b & 1;
    int mt  = (b >> 1) & 1;
    int ct  = b >> 2;              // 0..63
    int grp = b & 3;

    int tid  = threadIdx.x;
    int lane = tid & 63;
    int w    = tid >> 6;           // 0..7
    int fr   = lane & 15;
    int quad = lane >> 4;
    int sw   = fr & 7;

    int j0 = ct * 16;
    int row_base = mt * 128 + w * 16;
    int jcol = j0 + fr;

    const short* Wd = w_hh + (size_t)d * G3 * HH;

    // ---- stage W slice into LDS once (pre-swizzled source, linear dest) ----
    #pragma unroll
    for (int q = 0; q < 12; ++q) {
        int c  = w * 12 + q;               // 0..95
        int rr = c >> 1, kh = c & 1;       // rr: wrow 0..47, kh: half-row
        int g  = rr >> 4, jc = rr & 15;
        const short* src = Wd + (size_t)(g * HH + j0 + jc) * HH
                         + (size_t)(kh * 64 + (lane ^ (rr & 7))) * 8;
        GLOAD16(src, &Ws[rr * 1024 + kh * 512]);
    }

    // ---- per-lane pre-swizzled A source mapping (linear DMA dest decode) ----
    // dest byte = lane*16; decode through byte^=((row&7)<<4) swizzle:
    int l0 = lane & 1, l1 = (lane >> 1) & 1, l2 = (lane >> 2) & 1;
    int l3 = (lane >> 3) & 1, l4 = (lane >> 4) & 1, l5 = (lane >> 5) & 1;
    int arow = (l2 ^ l4) | (l3 << 1) | (l4 << 2) | (l5 << 3);   // 0..15
    int akb  = (l0 ^ l2 ^ l4) | ((l1 ^ l3) << 1);               // 0..3
    size_t a_src_off = (size_t)(row_base + arow) * HH + (size_t)akb * 8; // shorts

    // ---- persistent h registers ----
    float hreg[4];
    #pragma unroll
    for (int r = 0; r < 4; ++r) {
        int n = row_base + quad * 4 + r;
        hreg[r] = h[((size_t)d * NBAT + n) * HH + jcol];
    }
    float bhr = b_hh[d * G3 + jcol];
    float bhz = b_hh[d * G3 + HH + jcol];
    float bhn = b_hh[d * G3 + 2 * HH + jcol];

    __syncthreads();   // W staged (syncthreads drains vmcnt)

    // gi for step 0 (pipelined across barrier for later steps)
    float gir[4], giz[4], gin[4];
    {
        size_t gb0 = ((size_t)d * Mchunk) * G3 + jcol;
        #pragma unroll
        for (int r = 0; r < 4; ++r) {
            int n = row_base + quad * 4 + r;
            size_t gg = gb0 + (size_t)n * G3;
            gir[r] = gi[gg];
            giz[r] = gi[gg + HH];
            gin[r] = gi[gg + 2 * HH];
        }
    }

    for (int tt = 0; tt < Tc; ++tt) {
        int t = t0 + tt;
        const short* hb = hbf + ((size_t)((t & 1) * 2 + d)) * NBAT * HH;
        short*       ho = hbf + ((size_t)(((t + 1) & 1) * 2 + d)) * NBAT * HH;
        const short* asrc = hb + a_src_off;

        f32x4 acc[3];
        #pragma unroll
        for (int g = 0; g < 3; ++g) acc[g] = (f32x4){0.f, 0.f, 0.f, 0.f};

        // prologue: 3 chunks in flight
        #pragma unroll
        for (int c = 0; c < 3; ++c)
            GLOAD16(asrc + c * 32, &As[w][c][0]);

        int rd_off = (fr * 64 + quad * 16) ^ ((fr & 7) << 4);   // swizzled A read

        #pragma unroll
        for (int c = 0; c < 32; ++c) {
            // wait so that A(c) is complete: outstanding allowed = min(31-c, 2)
            if (c < 30)       asm volatile("s_waitcnt vmcnt(2)");
            else if (c == 30) asm volatile("s_waitcnt vmcnt(1)");
            else              asm volatile("s_waitcnt vmcnt(0)");
            __builtin_amdgcn_sched_barrier(0);
            s16x8 a = *(const s16x8*)((const char*)&As[w][c & 3][0] + rd_off);
            int ks = c * 4 + quad;
            #pragma unroll
            for (int g = 0; g < 3; ++g) {
                s16x8 bg = *(const s16x8*)&Ws[(g * 16 + fr) * 1024 + ((ks ^ sw) << 3)];
                acc[g] = __builtin_amdgcn_mfma_f32_16x16x32_bf16(a, bg, acc[g], 0, 0, 0);
            }
            __builtin_amdgcn_sched_barrier(0);
            if (c + 3 < 32)
                GLOAD16(asrc + (c + 3) * 32, &As[w][(c + 3) & 3][0]);
        }

        // ---- gates + state update ----
        #pragma unroll
        for (int r = 0; r < 4; ++r) {
            int n = row_base + quad * 4 + r;
            float hrv = acc[0][r] + bhr;
            float hzv = acc[1][r] + bhz;
            float hnv = acc[2][r] + bhn;
            float rg = 1.f / (1.f + __expf(-(gir[r] + hrv)));
            float zg = 1.f / (1.f + __expf(-(giz[r] + hzv)));
            float ng = tanhf(gin[r] + rg * hnv);
            float hnew = (1.f - zg) * ng + zg * hreg[r];
            hreg[r] = hnew;
            ho[(size_t)n * HH + jcol] = f2bf(hnew);
            size_t eidx = ((size_t)n * TT + t) * ENC_W + (size_t)d * HH + jcol;
            if (enc_bf) enc_bf[eidx] = f2bf(hnew);
            if (enc)    enc[eidx]    = hnew;
        }

        if (tt == Tc - 1) {   // persist fp32 h for the next chunk
            #pragma unroll
            for (int r = 0; r < 4; ++r) {
                int n = row_base + quad * 4 + r;
                h[((size_t)d * NBAT + n) * HH + jcol] = hreg[r];
            }
        } else {
            // prefetch next step's gi BEFORE the barrier: HBM latency overlaps spin
            size_t gbn = ((size_t)d * Mchunk + (size_t)(tt + 1) * NBAT) * G3 + jcol;
            #pragma unroll
            for (int r = 0; r < 4; ++r) {
                int n = row_base + quad * 4 + r;
                size_t gg = gbn + (size_t)n * G3;
                gir[r] = gi[gg];
                giz[r] = gi[gg + HH];
                gin[r] = gi[gg + 2 * HH];
            }
            // ---- inter-step barrier over the 64 blocks of group (d, mt) ----
            __syncthreads();                       // all waves' stores drained
            if (tid == 0) {
                unsigned int* c = &bar[grp * 32];
                __hip_atomic_fetch_add(c, 1u, __ATOMIC_RELEASE, __HIP_MEMORY_SCOPE_AGENT);
                unsigned tgt = 64u * (unsigned)(tt + 1);
                while (__hip_atomic_load(c, __ATOMIC_ACQUIRE, __HIP_MEMORY_SCOPE_AGENT) < tgt)
                    __builtin_amdgcn_s_sleep(2);
            }
            __syncthreads();
        }
    }
}

// ---------------- FC head ----------------
__global__ void bigru_fc(const float* __restrict__ enc, const float* __restrict__ fc_w,
                         const float* __restrict__ fc_b, float* __restrict__ out) {
    int n = blockIdx.x;
    int tid = threadIdx.x;
    __shared__ float hbuf[ENC_W];
    for (int k = tid; k < ENC_W; k += blockDim.x)
        hbuf[k] = enc[(size_t)n * TT * ENC_W + (size_t)(TT - 1) * ENC_W + k];
    __syncthreads();
    if (tid < NCLS) {
        float acc = fc_b[tid];
        for (int k = 0; k < ENC_W; ++k)
            acc += hbuf[k] * fc_w[(size_t)tid * ENC_W + k];
        out[(size_t)n * NCLS + tid] = acc;
    }
}

extern "C" void kernel_launch(void* const* d_in, const int* in_sizes, int n_in,
                              void* d_out, int out_size, void* d_ws, size_t ws_size,
                              hipStream_t stream) {
    const float* x        = (const float*)d_in[0];
    const float* bn_gamma = (const float*)d_in[1];
    const float* bn_beta  = (const float*)d_in[2];
    const float* w_ih[3]  = {(const float*)d_in[3], (const float*)d_in[7],  (const float*)d_in[11]};
    const float* w_hh[3]  = {(const float*)d_in[4], (const float*)d_in[8],  (const float*)d_in[12]};
    const float* b_ih[3]  = {(const float*)d_in[5], (const float*)d_in[9],  (const float*)d_in[13]};
    const float* b_hh[3]  = {(const float*)d_in[6], (const float*)d_in[10], (const float*)d_in[14]};
    const float* fc_w     = (const float*)d_in[15];
    const float* fc_b     = (const float*)d_in[16];

    float* out = (float*)d_out;
    float* enc = out + NBAT * NCLS;                       // [256][64][2048] fp32

    // ---- workspace bump allocator (256B aligned) ----
    char* base = (char*)d_ws;
    size_t off = 0;
    auto alloc = [&](size_t bytes) {
        void* p = base + off;
        off += (bytes + 255) & ~(size_t)255;
        return p;
    };
    float* mean      = (float*)alloc(IN0 * 4);
    float* istd      = (float*)alloc(IN0 * 4);
    short* xn_bf     = (short*)alloc((size_t)NBAT * TT * IN0P * 2);
    short* wih0_bf   = (short*)alloc((size_t)2 * G3 * IN0P * 2);
    short* wih_bf    = (short*)alloc((size_t)2 * G3 * ENC_W * 2);
    short* whh_bf    = (short*)alloc((size_t)2 * G3 * HH * 2);
    float* h         = (float*)alloc((size_t)2 * NBAT * HH * 4);
    short* hbf       = (short*)alloc((size_t)2 * 2 * NBAT * HH * 2);  // double buffer
    short* enc_bf    = (short*)alloc((size_t)NBAT * TT * ENC_W * 2);
    unsigned int* bar = (unsigned int*)alloc(4 * 32 * sizeof(unsigned int));
    size_t fixed = off;

    // pick largest Tc whose gi chunk fits in remaining ws
    int Tc = 1;
    for (int cand : {16, 8, 4, 2, 1}) {
        size_t gi_bytes = (size_t)2 * NBAT * cand * G3 * 4;
        if (fixed + gi_bytes + 1024 <= ws_size) { Tc = cand; break; }
    }
    float* gi = (float*)alloc((size_t)2 * NBAT * Tc * G3 * 4);
    int Mchunk = NBAT * Tc;

    // ---- BN ----
    bigru_bn_stats<<<IN0, 256, 0, stream>>>(x, mean, istd);
    bigru_bn_apply_bf16<<<(NBAT * TT * IN0P + 255) / 256, 256, 0, stream>>>(
        x, mean, istd, bn_gamma, bn_beta, xn_bf);

    // ---- weight conversions (layer-0 padded) ----
    bigru_cvt_wih0<<<(2 * G3 * IN0P + 255) / 256, 256, 0, stream>>>(w_ih[0], wih0_bf);

    for (int l = 0; l < 3; ++l) {
        if (l > 0) {
            int n4 = (2 * G3 * ENC_W) / 4;
            bigru_cvt4<<<(n4 + 255) / 256, 256, 0, stream>>>(w_ih[l], wih_bf, n4);
        }
        {
            int n4 = (2 * G3 * HH) / 4;
            bigru_cvt4<<<(n4 + 255) / 256, 256, 0, stream>>>(w_hh[l], whh_bf, n4);
        }
        hipMemsetAsync(h, 0, (size_t)2 * NBAT * HH * 4, stream);
        hipMemsetAsync(hbf, 0, (size_t)2 * 2 * NBAT * HH * 2, stream);

        const short* Abase = (l == 0) ? xn_bf : enc_bf;
        int ldA = (l == 0) ? IN0P : ENC_W;
        int K   = (l == 0) ? IN0P : ENC_W;
        const short* W = (l == 0) ? wih0_bf : wih_bf;

        for (int t0 = 0; t0 < TT; t0 += Tc) {
            bigru_gi_gemm<<<dim3(G3 / 128, Mchunk / 128, 2), 256, 0, stream>>>(
                Abase, ldA, K, W, b_ih[l], gi, t0, Mchunk);

            hipMemsetAsync(bar, 0, 4 * 32 * sizeof(unsigned int), stream);

            const short* whh_c   = whh_bf;
            const float* bhh_c   = b_hh[l];
            const float* gi_c    = gi;
            float*       h_c     = h;
            short*       hbf_c   = hbf;
            float*       enc_c   = (l == 2) ? enc : nullptr;
            short*       encbf_c = (l == 2) ? nullptr : enc_bf;
            unsigned int* bar_c  = bar;
            int a_t0 = t0, a_tc = Tc, a_mc = Mchunk;
            void* kargs[] = { &whh_c, &bhh_c, &gi_c, &h_c, &hbf_c,
                              &enc_c, &encbf_c, &bar_c, &a_t0, &a_tc, &a_mc };
            hipLaunchCooperativeKernel((const void*)bigru_steps_fused,
                                       dim3(256), dim3(512), kargs, 0, stream);
        }
    }

    bigru_fc<<<NBAT, 256, 0, stream>>>(enc, fc_w, fc_b, out);
}